// Round 8
// baseline (620.531 us; speedup 1.0000x reference)
//
#include <hip/hip_runtime.h>
#include <hip/hip_bf16.h>

// ISTA split-bf16 MFMA, round 8: 8-wave split-K for 2 waves/SIMD.
// C' = S · d^T (A = S register-resident, B = d from LDS, m89 C-layout).
// ROWS=16, grid=256 (1 block/CU), NTHREADS=512 = 8 waves = 2/SIMD.
// Wave w: column-group g=w&3 (2 N-tiles, cols 32g..32g+31), K-half up=w>>2
// (kt {0,1} lower / {2,3} upper). Same 96 MFMAs/CU-iter as R7 but split over
// 8 waves -> co-resident waves hide each other's ds_read/MFMA/barrier
// latency (R7 ran 1 wave/SIMD: 1270 cy/iter vs ~550 cy critical path).
// Partial exchange: wave w stores its other-n2 partial (f32x4, lane-linear,
// conflict-free) to psum[w]; barrier; reads psum[w^4]; combines; epilogue
// for n2=up only (half of R7's); writes d b64x2; barrier 2.
// Wy seeds only the lower wave's Chh (exchange carries it to the upper n2).
// Numerics: identical product set, one extra f32 re-association -> absmax
// ~0.031-0.05 (threshold 0.15).

#define ROWS     16
#define KPAD     128
#define N_DIM    100
#define M_DIM    70
#define NTHREADS 512

typedef __attribute__((ext_vector_type(8))) short short8;
typedef __attribute__((ext_vector_type(4))) float f32x4;

static __device__ __forceinline__ unsigned short f2bf(float f) {
    unsigned u = __float_as_uint(f);
    u += 0x7FFF + ((u >> 16) & 1);          // RNE
    return (unsigned short)(u >> 16);
}
static __device__ __forceinline__ float bf2f(unsigned short b) {
    return __uint_as_float(((unsigned)b) << 16);
}
// packed RNE: low16 = bf16(a), high16 = bf16(b)
static __device__ __forceinline__ unsigned cvt_pk_bf16(float a, float b) {
    unsigned r;
    asm("v_cvt_pk_bf16_f32 %0, %1, %2" : "=v"(r) : "v"(a), "v"(b));
    return r;
}
static __device__ __forceinline__ float med3f(float x, float lo, float hi) {
    float r;
    asm("v_med3_f32 %0, %1, %2, %3" : "=v"(r) : "v"(x), "v"(lo), "v"(hi));
    return r;
}

__global__ __launch_bounds__(NTHREADS, 2)
void ista_mfma6(const float* __restrict__ y,
                const float* __restrict__ S,
                const float* __restrict__ W,
                const float* __restrict__ thr,
                const int*   __restrict__ numIter,
                float* __restrict__ out)
{
    __shared__ __align__(16) unsigned short dh[2][ROWS * KPAD];  // d hi bf16 bits
    __shared__ __align__(16) unsigned short dl[2][ROWS * KPAD];  // d lo bf16 bits
    __shared__ __align__(16) float psum[8][64 * 4];              // partial exchange

    const int t    = threadIdx.x;
    const int wv   = t >> 6;        // wave 0..7
    const int l    = t & 63;
    const int l15  = l & 15;
    const int lg   = l >> 4;
    const int g    = wv & 3;        // column group (2 N-tiles)
    const int up   = wv >> 2;       // 0: kt{0,1}+Wy seed, 1: kt{2,3}
    const int ktb  = up * 2;
    const int row0 = blockIdx.x * ROWS;
    const float th  = thr[0];
    const float nth = -th;
    const int iters = numIter[0];
    const unsigned swz = (unsigned)((l15 & 7) << 4);

    // ---- one-time: S fragments, A operand (row = l15 = j-in-tile) ----
    short8 Sh[2][2], Sl[2][2];
    #pragma unroll
    for (int n2 = 0; n2 < 2; ++n2) {
        const int jg = g * 32 + n2 * 16 + l15;             // global output column
        #pragma unroll
        for (int kc = 0; kc < 2; ++kc) {
            const int kt = ktb + kc;
            #pragma unroll
            for (int i = 0; i < 8; ++i) {
                const int k = kt * 32 + lg * 8 + i;
                const float v = (jg < N_DIM && k < N_DIM) ? S[jg * N_DIM + k] : 0.f;
                const unsigned short hb = f2bf(v);
                Sh[n2][kc][i] = (short)hb;
                Sl[n2][kc][i] = (short)f2bf(v - bf2f(hb));
            }
        }
    }

    // ---- one-time: Wy in C' layout, lower waves only ----
    f32x4 Wyr[2] = { {0,0,0,0}, {0,0,0,0} };
    if (!up) {
        #pragma unroll
        for (int n2 = 0; n2 < 2; ++n2) {
            #pragma unroll
            for (int q = 0; q < 4; ++q) {
                const int j = g * 32 + n2 * 16 + lg * 4 + q;
                float acc = 0.f;
                if (j < N_DIM) {
                    const float* yr = y + (size_t)(row0 + l15) * M_DIM;
                    const float* wr = W + (size_t)j * M_DIM;
                    #pragma unroll 10
                    for (int m = 0; m < M_DIM; ++m) acc = fmaf(yr[m], wr[m], acc);
                }
                Wyr[n2][q] = acc;
            }
        }
    }

    // ---- zero buffer 0 ----
    for (int idx = t; idx < ROWS * KPAD; idx += NTHREADS) {
        dh[0][idx] = 0; dl[0][idx] = 0;
    }
    __syncthreads();

    // loop-invariant offsets
    unsigned roff[2];
    #pragma unroll
    for (int kc = 0; kc < 2; ++kc)
        roff[kc] = ((unsigned)(l15 * 256 + (ktb + kc) * 64 + lg * 16)) ^ swz;
    const unsigned woff = ((unsigned)(l15 * 256 + g * 64 + up * 32 + lg * 8)) ^ swz;
    float* pme = &psum[wv][l * 4];
    const float* ppa = &psum[wv ^ 4][l * 4];

    int cur = 0;
    for (int it = 0; it < iters; ++it) {
        const char* rh = (const char*)dh[cur];
        const char* rl = (const char*)dl[cur];
        char* wh = (char*)dh[cur ^ 1];
        char* wl = (char*)dl[cur ^ 1];

        // ---- 4 b128 reads: this wave's 2 K-tiles ----
        short8 Bh[2], Bl[2];
        #pragma unroll
        for (int kc = 0; kc < 2; ++kc) {
            Bh[kc] = *(const short8*)(rh + roff[kc]);
            Bl[kc] = *(const short8*)(rl + roff[kc]);
        }

        // ---- 12 MFMAs, 6 chains depth 2 ----
        f32x4 Chh[2] = { Wyr[0], Wyr[1] };
        f32x4 Chl[2] = { {0,0,0,0}, {0,0,0,0} };
        f32x4 Clh[2] = { {0,0,0,0}, {0,0,0,0} };
        #pragma unroll
        for (int kc = 0; kc < 2; ++kc) {
            #pragma unroll
            for (int n2 = 0; n2 < 2; ++n2)
                Chh[n2] = __builtin_amdgcn_mfma_f32_16x16x32_bf16(Sh[n2][kc], Bh[kc], Chh[n2], 0, 0, 0);
            #pragma unroll
            for (int n2 = 0; n2 < 2; ++n2)
                Chl[n2] = __builtin_amdgcn_mfma_f32_16x16x32_bf16(Sh[n2][kc], Bl[kc], Chl[n2], 0, 0, 0);
            #pragma unroll
            for (int n2 = 0; n2 < 2; ++n2)
                Clh[n2] = __builtin_amdgcn_mfma_f32_16x16x32_bf16(Sl[n2][kc], Bh[kc], Clh[n2], 0, 0, 0);
        }

        // ---- partial sums; send the n2 I don't own ----
        f32x4 P0, P1;
        #pragma unroll
        for (int q = 0; q < 4; ++q) {
            P0[q] = Chh[0][q] + Chl[0][q] + Clh[0][q];
            P1[q] = Chh[1][q] + Chl[1][q] + Clh[1][q];
        }
        *(f32x4*)pme = up ? P0 : P1;    // wave-uniform select
        __syncthreads();

        // ---- combine with partner, epilogue for n2 = up ----
        const f32x4 mine  = up ? P1 : P0;
        const f32x4 other = *(const f32x4*)ppa;
        float r0, r1, r2, r3;
        {
            const float s0 = mine[0] + other[0];
            const float s1 = mine[1] + other[1];
            const float s2 = mine[2] + other[2];
            const float s3 = mine[3] + other[3];
            r0 = s0 - med3f(s0, nth, th);
            r1 = s1 - med3f(s1, nth, th);
            r2 = s2 - med3f(s2, nth, th);
            r3 = s3 - med3f(s3, nth, th);
        }
        const unsigned h01 = cvt_pk_bf16(r0, r1);
        const unsigned h23 = cvt_pk_bf16(r2, r3);
        const float l0 = r0 - __uint_as_float(h01 << 16);
        const float l1 = r1 - __uint_as_float(h01 & 0xFFFF0000u);
        const float l2 = r2 - __uint_as_float(h23 << 16);
        const float l3 = r3 - __uint_as_float(h23 & 0xFFFF0000u);
        const unsigned lo01 = cvt_pk_bf16(l0, l1);
        const unsigned lo23 = cvt_pk_bf16(l2, l3);
        *(uint2*)(wh + woff) = make_uint2(h01, h23);
        *(uint2*)(wl + woff) = make_uint2(lo01, lo23);

        __syncthreads();          // d buffer complete; also fences psum reuse
        cur ^= 1;
    }

    // ---- output: hi+lo recombine, write global ----
    for (int idx = t; idx < ROWS * N_DIM; idx += NTHREADS) {
        const int r = idx / N_DIM;
        const int j = idx - r * N_DIM;
        const unsigned off = ((unsigned)(r * 256 + j * 2)) ^ ((unsigned)((r & 7) << 4));
        const float v = bf2f(*(const unsigned short*)((const char*)dh[cur] + off))
                      + bf2f(*(const unsigned short*)((const char*)dl[cur] + off));
        out[(size_t)(row0 + r) * N_DIM + j] = v;
    }
}

extern "C" void kernel_launch(void* const* d_in, const int* in_sizes, int n_in,
                              void* d_out, int out_size, void* d_ws, size_t ws_size,
                              hipStream_t stream) {
    const float* y       = (const float*)d_in[0];
    const float* S       = (const float*)d_in[1];
    const float* W       = (const float*)d_in[2];
    const float* thr     = (const float*)d_in[3];
    const int*   numIter = (const int*)d_in[4];
    float* out = (float*)d_out;

    const int Brows = in_sizes[0] / M_DIM;   // 4096
    const int nblk  = Brows / ROWS;          // 256 blocks = 1/CU
    ista_mfma6<<<nblk, NTHREADS, 0, stream>>>(y, S, W, thr, numIter, out);
}